// Round 11
// baseline (234.738 us; speedup 1.0000x reference)
//
#include <hip/hip_runtime.h>

typedef unsigned short u16;
typedef unsigned int   u32;

using short8 = __attribute__((ext_vector_type(8))) short;
using f32x4  = __attribute__((ext_vector_type(4))) float;
using half4  = __attribute__((ext_vector_type(4))) _Float16;
using half8  = __attribute__((ext_vector_type(8))) _Float16;

// SCALE * log2(e) folded into q at the QKV epilogue
#define QSCALE 0.18033688011112042f

__device__ __forceinline__ u16 f2bf(float f) {
  u32 u = __float_as_uint(f);
  return (u16)((u + 0x8000u) >> 16);
}
__device__ __forceinline__ u16 f2h(float f) {
  _Float16 h = (_Float16)f;
  return __builtin_bit_cast(u16, h);
}

// async global->LDS DMA, 16B per lane; lds dest = wave-uniform base + lane*16
__device__ __forceinline__ void gld16(const u16* g, u16* l) {
  __builtin_amdgcn_global_load_lds(
      (const __attribute__((address_space(1))) unsigned int*)g,
      (__attribute__((address_space(3))) unsigned int*)l, 16, 0, 0);
}

// ---------------- x fp32 -> bf16, 4 elems/thread ----------------
__global__ __launch_bounds__(256) void cvt_x(const float* __restrict__ in,
                                             u16* __restrict__ out) {
  int idx = blockIdx.x * 256 + threadIdx.x;
  float4 v = reinterpret_cast<const float4*>(in)[idx];
  ushort4 o;
  o.x = f2bf(v.x); o.y = f2bf(v.y); o.z = f2bf(v.z); o.w = f2bf(v.w);
  reinterpret_cast<ushort4*>(out)[idx] = o;
}

// ---------------- fp32 [R][C] -> bf16 [C][R] (B^T layout for GEMM) ----------------
__global__ __launch_bounds__(256) void transpose_w(const float* __restrict__ in,
                                                   u16* __restrict__ out,
                                                   int R, int C) {
  __shared__ u32 s[32][33];
  int c0 = blockIdx.x * 32, r0 = blockIdx.y * 32;
  int j = threadIdx.x & 31, i0 = threadIdx.x >> 5;
#pragma unroll
  for (int p = 0; p < 4; ++p) {
    int i = i0 + p * 8;
    s[i][j] = f2bf(in[(size_t)(r0 + i) * C + c0 + j]);
  }
  __syncthreads();
#pragma unroll
  for (int p = 0; p < 4; ++p) {
    int jj = i0 + p * 8;
    out[(size_t)(c0 + jj) * R + r0 + j] = (u16)s[j][jj];
  }
}

// ---------------- QKV GEMM, pipelined (r8 structure) --- INSTRUMENTATION ----
// MEASUREMENT ROUND: the K-loop runs REP=3 times, accumulating (all passes
// live -> no DCE), epilogue scales by 1/REP (error <= 2ulp << tolerance).
// Purpose: per-dispatch duration becomes ~3x the true K-loop time so this
// kernel finally appears in the rocprof top-5 WITH counters (attn has flooded
// the table all session). True qkv K-loop time = (total - 188.3)/2.
__global__ __launch_bounds__(256, 2) void gemm_qkv(
    const u16* __restrict__ A, const u16* __restrict__ Bt,
    const float* __restrict__ bias,
    u16* __restrict__ q_out, u16* __restrict__ k_out, u16* __restrict__ vt_out) {
  const int K = 1024;
  __shared__ __align__(16) u16 As[4][128 * 32];  // 32 KB
  __shared__ __align__(16) u16 Bs[4][192 * 32];  // 48 KB
  const int tid = threadIdx.x;
  const int lane = tid & 63, wv = tid >> 6;
  const int l16 = lane & 15, quad = lane >> 4;
  const int wm = wv & 1, wn = wv >> 1;
  const int bx = blockIdx.x, by = blockIdx.y;

  const u16* Ab = A + (size_t)by * 128 * K;
  const u16* Bb = Bt + (size_t)bx * 192 * K;

  const int iA0 = tid, iA1 = 256 + tid;
  const int iB0 = tid, iB1 = 256 + tid, iB2 = 512 + tid;
  const int dA0 = iA0 << 3, dA1 = iA1 << 3;
  const int dB0 = iB0 << 3, dB1 = iB1 << 3, dB2 = iB2 << 3;

  int aoff[4], boff[6];
#pragma unroll
  for (int mi = 0; mi < 4; ++mi) {
    int r = wm * 64 + mi * 16 + l16;
    aoff[mi] = r * 32 + ((quad ^ (r & 3)) << 3);
  }
#pragma unroll
  for (int ni = 0; ni < 6; ++ni) {
    int r = wn * 96 + ni * 16 + l16;
    boff[ni] = r * 32 + ((quad ^ (r & 3)) << 3);
  }

  const f32x4 fzero = {0.0f, 0.0f, 0.0f, 0.0f};
  f32x4 acc[4][6];
#pragma unroll
  for (int i = 0; i < 4; ++i)
#pragma unroll
    for (int j = 0; j < 6; ++j) acc[i][j] = fzero;

#define STAGE_A(T)                        \
  do {                                    \
    gld16(sA0, &As[T][dA0]);              \
    gld16(sA1, &As[T][dA1]);              \
    sA0 += 32; sA1 += 32;                 \
  } while (0)
#define STAGE_B(T)                        \
  do {                                    \
    gld16(sB0, &Bs[T][dB0]);              \
    gld16(sB1, &Bs[T][dB1]);              \
    gld16(sB2, &Bs[T][dB2]);              \
    sB0 += 32; sB1 += 32; sB2 += 32;      \
  } while (0)
#define VM5 asm volatile("s_waitcnt vmcnt(5)" ::: "memory")
#define VM0 asm volatile("s_waitcnt vmcnt(0)" ::: "memory")

#define GTILE(S, T, DOST, VW)                                              \
  do {                                                                     \
    short8 bb[6];                                                          \
    _Pragma("unroll")                                                      \
    for (int j = 0; j < 6; ++j)                                            \
      bb[j] = *reinterpret_cast<const short8*>(&Bs[S][boff[j]]);           \
    short8 a0 = *reinterpret_cast<const short8*>(&As[S][aoff[0]]);         \
    short8 a1 = *reinterpret_cast<const short8*>(&As[S][aoff[1]]);         \
    if (DOST) { STAGE_A(T); }                                              \
    __builtin_amdgcn_s_barrier();                                          \
    __builtin_amdgcn_s_setprio(1);                                         \
    _Pragma("unroll")                                                      \
    for (int j = 0; j < 6; ++j) {                                          \
      acc[0][j] = __builtin_amdgcn_mfma_f32_16x16x32_bf16(a0, bb[j], acc[0][j], 0, 0, 0); \
      acc[1][j] = __builtin_amdgcn_mfma_f32_16x16x32_bf16(a1, bb[j], acc[1][j], 0, 0, 0); \
    }                                                                      \
    __builtin_amdgcn_s_setprio(0);                                         \
    __builtin_amdgcn_s_barrier();                                          \
    short8 a2 = *reinterpret_cast<const short8*>(&As[S][aoff[2]]);         \
    short8 a3 = *reinterpret_cast<const short8*>(&As[S][aoff[3]]);         \
    if (DOST) { STAGE_B(T); }                                              \
    __builtin_amdgcn_s_barrier();                                          \
    __builtin_amdgcn_s_setprio(1);                                         \
    _Pragma("unroll")                                                      \
    for (int j = 0; j < 6; ++j) {                                          \
      acc[2][j] = __builtin_amdgcn_mfma_f32_16x16x32_bf16(a2, bb[j], acc[2][j], 0, 0, 0); \
      acc[3][j] = __builtin_amdgcn_mfma_f32_16x16x32_bf16(a3, bb[j], acc[3][j], 0, 0, 0); \
    }                                                                      \
    __builtin_amdgcn_s_setprio(0);                                         \
    VW;                                                                    \
    __builtin_amdgcn_s_barrier();                                          \
  } while (0)

#pragma unroll 1
  for (int rep = 0; rep < 3; ++rep) {
    // staging source pointers re-derived per rep (swizzle folded once)
    const u16* sA0 = Ab + (size_t)(iA0 >> 2) * K + (((iA0 & 3) ^ ((iA0 >> 2) & 3)) << 3);
    const u16* sA1 = Ab + (size_t)(iA1 >> 2) * K + (((iA1 & 3) ^ ((iA1 >> 2) & 3)) << 3);
    const u16* sB0 = Bb + (size_t)(iB0 >> 2) * K + (((iB0 & 3) ^ ((iB0 >> 2) & 3)) << 3);
    const u16* sB1 = Bb + (size_t)(iB1 >> 2) * K + (((iB1 & 3) ^ ((iB1 >> 2) & 3)) << 3);
    const u16* sB2 = Bb + (size_t)(iB2 >> 2) * K + (((iB2 & 3) ^ ((iB2 >> 2) & 3)) << 3);

    STAGE_A(0); STAGE_B(0);
    STAGE_A(1); STAGE_B(1);
    VM5;
    __builtin_amdgcn_s_barrier();

    for (int kb = 0; kb < 28; kb += 4) {
      GTILE(0, 2, 1, VM5);
      GTILE(1, 3, 1, VM5);
      GTILE(2, 0, 1, VM5);
      GTILE(3, 1, 1, VM5);
    }
    GTILE(0, 2, 1, VM5);
    GTILE(1, 3, 1, VM5);
    GTILE(2, 0, 0, VM0);
    GTILE(3, 1, 0, ((void)0));
  }
#undef GTILE
#undef STAGE_A
#undef STAGE_B

  // epilogue: scale by 1/REP, then QKV scatter (verified semantics)
#pragma unroll
  for (int mi = 0; mi < 4; ++mi)
#pragma unroll
    for (int ni = 0; ni < 6; ++ni) {
      int col = bx * 192 + wn * 96 + ni * 16 + l16;
      float bv = bias[col];
      int row0 = by * 128 + wm * 64 + mi * 16 + quad * 4;
      int which = col >> 10, rem = col & 1023;
      int h = rem >> 6, d = rem & 63;
      int b = row0 >> 11, sq0 = row0 & 2047;
      int bh = (b << 4) + h;
      const float rscale = 1.0f / 3.0f;
      if (which == 2) {
        ushort4 pk;
        pk.x = f2h(acc[mi][ni][0] * rscale + bv);
        pk.y = f2h(acc[mi][ni][1] * rscale + bv);
        pk.z = f2h(acc[mi][ni][2] * rscale + bv);
        pk.w = f2h(acc[mi][ni][3] * rscale + bv);
        size_t off = (size_t)bh * 131072 +
                     (((sq0 >> 2) * 16 + (d & 15)) * 16 + ((d >> 4) << 2));
        *reinterpret_cast<ushort4*>(&vt_out[off]) = pk;
      } else {
        size_t base = (size_t)(bh * 2048 + sq0) * 64 + d;
#pragma unroll
        for (int r = 0; r < 4; ++r) {
          float val = acc[mi][ni][r] * rscale + bv;
          if (which == 0) q_out[base + r * 64] = f2bf(val * QSCALE);
          else            k_out[base + r * 64] = f2bf(val);
        }
      }
    }
}

// ---------------- bf16 MFMA GEMM (out-proj): C[M,N] = A @ Bt^T + bias -------
template <int EPI, int MT>
__global__ __launch_bounds__(256, 3) void gemm_bt(
    const u16* __restrict__ A, const u16* __restrict__ Bt,
    const float* __restrict__ bias, float* __restrict__ c_out,
    u16* __restrict__ q_out, u16* __restrict__ k_out, u16* __restrict__ vt_out,
    int M, int N, int K) {
  __shared__ __align__(16) u16 As[32 * MT * 32];
  __shared__ __align__(16) u16 Bs[128 * 32];
  const int tid = threadIdx.x;
  const int lane = tid & 63;
  const int wv = tid >> 6;
  const int l16 = lane & 15, quad = lane >> 4;
  const int wm = wv & 1, wn = wv >> 1;
  const int bx = blockIdx.x, by = blockIdx.y;

  const u16* Ab = A + (size_t)by * (32 * MT) * K;
  const u16* Bb = Bt + (size_t)bx * 128 * K;

  const f32x4 fzero = {0.0f, 0.0f, 0.0f, 0.0f};
  f32x4 acc[MT][4];
#pragma unroll
  for (int i = 0; i < MT; ++i)
#pragma unroll
    for (int j = 0; j < 4; ++j) acc[i][j] = fzero;

  for (int k0 = 0; k0 < K; k0 += 32) {
    __syncthreads();
#pragma unroll
    for (int p = 0; p < MT / 2; ++p) {
      int id = p * 256 + tid;
      int row = id >> 2, blk = id & 3;
      int gc = k0 + ((blk ^ (row & 3)) << 3);
      gld16(Ab + (size_t)row * K + gc, &As[id << 3]);
    }
#pragma unroll
    for (int p = 0; p < 2; ++p) {
      int id = p * 256 + tid;
      int row = id >> 2, blk = id & 3;
      int gc = k0 + ((blk ^ (row & 3)) << 3);
      gld16(Bb + (size_t)row * K + gc, &Bs[id << 3]);
    }
    __syncthreads();
    short8 af[MT], bfr[4];
#pragma unroll
    for (int mi = 0; mi < MT; ++mi) {
      int row = wm * (MT * 16) + mi * 16 + l16;
      af[mi] = *reinterpret_cast<const short8*>(&As[row * 32 + ((quad ^ (row & 3)) << 3)]);
    }
#pragma unroll
    for (int ni = 0; ni < 4; ++ni) {
      int row = wn * 64 + ni * 16 + l16;
      bfr[ni] = *reinterpret_cast<const short8*>(&Bs[row * 32 + ((quad ^ (row & 3)) << 3)]);
    }
#pragma unroll
    for (int mi = 0; mi < MT; ++mi)
#pragma unroll
      for (int ni = 0; ni < 4; ++ni)
        acc[mi][ni] = __builtin_amdgcn_mfma_f32_16x16x32_bf16(af[mi], bfr[ni], acc[mi][ni], 0, 0, 0);
  }

#pragma unroll
  for (int mi = 0; mi < MT; ++mi)
#pragma unroll
    for (int ni = 0; ni < 4; ++ni) {
      int col = bx * 128 + wn * 64 + ni * 16 + l16;
      float bv = bias[col];
      int row0 = by * (32 * MT) + wm * (MT * 16) + mi * 16 + quad * 4;
      if (EPI == 1) {
#pragma unroll
        for (int r = 0; r < 4; ++r)
          c_out[(size_t)(row0 + r) * N + col] = acc[mi][ni][r] + bv;
      } else {
        int which = col >> 10, rem = col & 1023;
        int h = rem >> 6, d = rem & 63;
        int b = row0 >> 11, sq0 = row0 & 2047;
        int bh = (b << 4) + h;
        if (which == 2) {
          ushort4 pk;
          pk.x = f2h(acc[mi][ni][0] + bv);
          pk.y = f2h(acc[mi][ni][1] + bv);
          pk.z = f2h(acc[mi][ni][2] + bv);
          pk.w = f2h(acc[mi][ni][3] + bv);
          size_t off = (size_t)bh * 131072 +
                       (((sq0 >> 2) * 16 + (d & 15)) * 16 + ((d >> 4) << 2));
          *reinterpret_cast<ushort4*>(&vt_out[off]) = pk;
        } else {
          size_t base = (size_t)(bh * 2048 + sq0) * 64 + d;
#pragma unroll
          for (int r = 0; r < 4; ++r) {
            float val = acc[mi][ni][r] + bv;
            if (which == 0) q_out[base + r * 64] = f2bf(val * QSCALE);
            else            k_out[base + r * 64] = f2bf(val);
          }
        }
      }
    }
}

// ---------------- flash attention (r7 version: best measured, 51.2 us) ------
__global__ __launch_bounds__(256, 4) void attn(
    const u16* __restrict__ q_buf, const u16* __restrict__ k_buf,
    const u16* __restrict__ vt_buf, u16* __restrict__ o_buf) {
  __shared__ __align__(16) u16 Ks[2][4096];
  __shared__ __align__(16) u16 Vs[2][4096];

  const int tid = threadIdx.x;
  const int lane = tid & 63, w = tid >> 6;
  const int l16 = lane & 15, quad = lane >> 4;
  const int bh = blockIdx.x, q0 = blockIdx.y * 64;

  const u16* qg = q_buf + (size_t)bh * 131072 + (q0 + w * 16) * 64;
  const u16* kg = k_buf + (size_t)bh * 131072;
  const u16* vg = vt_buf + (size_t)bh * 131072;

  short8 qb[2];
#pragma unroll
  for (int kk = 0; kk < 2; ++kk)
    qb[kk] = *reinterpret_cast<const short8*>(qg + l16 * 64 + kk * 32 + quad * 8);

  const int idA = tid, idB = 256 + tid;
  const u16* ksA = kg + (idA >> 3) * 64 + (((idA & 7) ^ ((idA >> 3) & 7)) << 3);
  const u16* ksB = kg + (idB >> 3) * 64 + (((idB & 7) ^ ((idB >> 3) & 7)) << 3);
  const u16* vsA = vg + ((idA ^ ((idA >> 4) & 1)) << 3);
  const u16* vsB = vg + ((idB ^ ((idB >> 4) & 1)) << 3);
  const int ldA = idA << 3, ldB = idB << 3;

  int k0o[4], k1o[4], v0o[4], v1o[4];
#pragma unroll
  for (int t = 0; t < 4; ++t) {
    int rr = t * 16 + l16;
    k0o[t] = rr * 64 + ((quad ^ (rr & 7)) << 3);
    k1o[t] = rr * 64 + (((4 + quad) ^ (rr & 7)) << 3);
    int gb = (t * 4 + quad) * 32 + l16 * 2;
    int sw = (l16 >> 3) & 1;
    v0o[t] = (gb + sw) << 3;
    v1o[t] = (gb + (sw ^ 1)) << 3;
  }

  const f32x4 fzero = {0.0f, 0.0f, 0.0f, 0.0f};
  f32x4 o_acc[4];
  float l_acc = 0.f;
#pragma unroll
  for (int nd = 0; nd < 4; ++nd) o_acc[nd] = fzero;

#define STAGE(BUF)                           \
  do {                                       \
    gld16(ksA, &Ks[BUF][ldA]);               \
    gld16(ksB, &Ks[BUF][ldB]);               \
    gld16(vsA, &Vs[BUF][ldA]);               \
    gld16(vsB, &Vs[BUF][ldB]);               \
    ksA += 4096; ksB += 4096;                \
    vsA += 4096; vsB += 4096;                \
  } while (0)

#define TILE(BUF)                                                         \
  do {                                                                    \
    _Pragma("unroll")                                                     \
    for (int t = 0; t < 4; ++t) {                                         \
      short8 k0f = *reinterpret_cast<const short8*>(&Ks[BUF][k0o[t]]);    \
      short8 k1f = *reinterpret_cast<const short8*>(&Ks[BUF][k1o[t]]);    \
      half8 v0 = *reinterpret_cast<const half8*>(&Vs[BUF][v0o[t]]);       \
      half8 v1 = *reinterpret_cast<const half8*>(&Vs[BUF][v1o[t]]);       \
      half4 vb0 = __builtin_shufflevector(v0, v0, 0, 1, 2, 3);            \
      half4 vb1 = __builtin_shufflevector(v0, v0, 4, 5, 6, 7);            \
      half4 vb2 = __builtin_shufflevector(v1, v1, 0, 1, 2, 3);            \
      half4 vb3 = __builtin_shufflevector(v1, v1, 4, 5, 6, 7);            \
      __builtin_amdgcn_s_setprio(1);                                      \
      f32x4 s = __builtin_amdgcn_mfma_f32_16x16x32_bf16(k0f, qb[0], fzero, 0, 0, 0); \
      s = __builtin_amdgcn_mfma_f32_16x16x32_bf16(k1f, qb[1], s, 0, 0, 0);\
      __builtin_amdgcn_s_setprio(0);                                      \
      float p0 = __builtin_amdgcn_exp2f(s[0]);                            \
      float p1 = __builtin_amdgcn_exp2f(s[1]);                            \
      float p2 = __builtin_amdgcn_exp2f(s[2]);                            \
      float p3 = __builtin_amdgcn_exp2f(s[3]);                            \
      l_acc += (p0 + p1) + (p2 + p3);                                     \
      half4 pa;                                                           \
      pa[0] = (_Float16)p0; pa[1] = (_Float16)p1;                         \
      pa[2] = (_Float16)p2; pa[3] = (_Float16)p3;                         \
      __builtin_amdgcn_s_setprio(1);                                      \
      o_acc[0] = __builtin_amdgcn_mfma_f32_16x16x16f16(pa, vb0, o_acc[0], 0, 0, 0); \
      o_acc[1] = __builtin_amdgcn_mfma_f32_16x16x16f16(pa, vb1, o_acc[1], 0, 0, 0); \
      o_acc[2] = __builtin_amdgcn_mfma_f32_16x16x16f16(pa, vb2, o_acc[2], 0, 0, 0); \
      o_acc[3] = __builtin_amdgcn_mfma_f32_16x16x16f16(pa, vb3, o_acc[3], 0, 0, 0); \
      __builtin_amdgcn_s_setprio(0);                                      \
    }                                                                     \
  } while (0)

  STAGE(0);
  __syncthreads();

  for (int i = 0; i < 32; i += 2) {
    if (i + 1 < 32) STAGE(1);
    TILE(0);
    __syncthreads();
    if (i + 2 < 32) STAGE(0);
    TILE(1);
    __syncthreads();
  }
#undef STAGE
#undef TILE

  l_acc += __shfl_xor(l_acc, 16, 64);
  l_acc += __shfl_xor(l_acc, 32, 64);

  const int b = bh >> 4, h = bh & 15;
  float lv[4];
#pragma unroll
  for (int r = 0; r < 4; ++r)
    lv[r] = __shfl(l_acc, quad * 4 + r, 64);
#pragma unroll
  for (int nd = 0; nd < 4; ++nd) {
#pragma unroll
    for (int r = 0; r < 4; ++r) {
      int sq = q0 + w * 16 + quad * 4 + r;
      o_buf[(size_t)(b * 2048 + sq) * 1024 + h * 64 + nd * 16 + l16] =
          f2bf(o_acc[nd][r] / lv[r]);
    }
  }
}

extern "C" void kernel_launch(void* const* d_in, const int* in_sizes, int n_in,
                              void* d_out, int out_size, void* d_ws, size_t ws_size,
                              hipStream_t stream) {
  (void)in_sizes; (void)n_in; (void)out_size; (void)ws_size;
  const float* x     = (const float*)d_in[0];
  const float* W_qkv = (const float*)d_in[1];
  const float* b_qkv = (const float*)d_in[2];
  const float* W_out = (const float*)d_in[3];
  const float* b_out = (const float*)d_in[4];
  float* out = (float*)d_out;

  // workspace layout (48 MB total)
  char* ws = (char*)d_ws;
  u16* x_bf   = (u16*)(ws);              //  8 MB  [4096][1024] bf16
  u16* wqkv_t = (u16*)(ws + 8388608);    //  6 MB  [3072][1024] bf16
  u16* wout_t = (u16*)(ws + 14680064);   //  2 MB  [1024][1024] bf16
  u16* q_buf  = (u16*)(ws + 16777216);   //  8 MB  [32][2048][64] bf16
  u16* k_buf  = (u16*)(ws + 25165824);   //  8 MB  [32][2048][64] bf16
  u16* vt_buf = (u16*)(ws + 33554432);   //  8 MB  [32] V-frag fp16 layout
  u16* o_bf   = (u16*)(ws + 41943040);   //  8 MB  [4096][1024] bf16

  cvt_x<<<4096, 256, 0, stream>>>(x, x_bf);
  transpose_w<<<dim3(96, 32), 256, 0, stream>>>(W_qkv, wqkv_t, 1024, 3072);
  transpose_w<<<dim3(32, 32), 256, 0, stream>>>(W_out, wout_t, 1024, 1024);
  gemm_qkv<<<dim3(16, 32), 256, 0, stream>>>(x_bf, wqkv_t, b_qkv,
                                             q_buf, k_buf, vt_buf);
  attn<<<dim3(32, 32), 256, 0, stream>>>(q_buf, k_buf, vt_buf, o_bf);
  gemm_bt<1, 2><<<dim3(8, 64), 256, 0, stream>>>(o_bf, wout_t, b_out, out,
                                                 nullptr, nullptr, nullptr, 4096, 1024, 1024);
}

// Round 12
// 184.323 us; speedup vs baseline: 1.2735x; 1.2735x over previous
//
#include <hip/hip_runtime.h>

typedef unsigned short u16;
typedef unsigned int   u32;

using short8 = __attribute__((ext_vector_type(8))) short;
using f32x4  = __attribute__((ext_vector_type(4))) float;
using half4  = __attribute__((ext_vector_type(4))) _Float16;
using half8  = __attribute__((ext_vector_type(8))) _Float16;

// SCALE * log2(e) folded into q at the QKV epilogue
#define QSCALE 0.18033688011112042f
// conflict-free chunk swizzle: rows r..r+12 -> 4 distinct chunk slots
// (old (r&3) repeated every 4 rows -> 4-way ds_read bank conflict, measured
// 7.86M SQ_LDS_BANK_CONFLICT in r11's instrumented qkv)
#define SXR(r) ((((r) ^ ((r) >> 2))) & 3)

__device__ __forceinline__ u16 f2bf(float f) {
  u32 u = __float_as_uint(f);
  return (u16)((u + 0x8000u) >> 16);
}
__device__ __forceinline__ u16 f2h(float f) {
  _Float16 h = (_Float16)f;
  return __builtin_bit_cast(u16, h);
}

// async global->LDS DMA, 16B per lane; lds dest = wave-uniform base + lane*16
__device__ __forceinline__ void gld16(const u16* g, u16* l) {
  __builtin_amdgcn_global_load_lds(
      (const __attribute__((address_space(1))) unsigned int*)g,
      (__attribute__((address_space(3))) unsigned int*)l, 16, 0, 0);
}

// ---------------- fused preprocessing: cvt_x + transpose(W_qkv) + transpose(W_out)
// one launch instead of three (tests the launch-gap hypothesis).
// blocks [0,4096): x fp32->bf16 ; [4096,7168): W_qkv^T ; [7168,8192): W_out^T
__global__ __launch_bounds__(256) void prep(
    const float* __restrict__ x, u16* __restrict__ x_bf,
    const float* __restrict__ Wq, u16* __restrict__ wq_t,
    const float* __restrict__ Wo, u16* __restrict__ wo_t) {
  __shared__ u32 s[32][33];
  const int bid = blockIdx.x, tid = threadIdx.x;
  if (bid < 4096) {
    int idx = bid * 256 + tid;
    float4 v = reinterpret_cast<const float4*>(x)[idx];
    ushort4 o;
    o.x = f2bf(v.x); o.y = f2bf(v.y); o.z = f2bf(v.z); o.w = f2bf(v.w);
    reinterpret_cast<ushort4*>(x_bf)[idx] = o;
    return;
  }
  const float* in; u16* out; int R, C, bx, by;
  if (bid < 7168) { int b = bid - 4096; in = Wq; out = wq_t; R = 1024; C = 3072; bx = b % 96; by = b / 96; }
  else            { int b = bid - 7168; in = Wo; out = wo_t; R = 1024; C = 1024; bx = b % 32; by = b / 32; }
  int c0 = bx * 32, r0 = by * 32;
  int j = tid & 31, i0 = tid >> 5;
#pragma unroll
  for (int p = 0; p < 4; ++p) {
    int i = i0 + p * 8;
    s[i][j] = f2bf(in[(size_t)(r0 + i) * C + c0 + j]);
  }
  __syncthreads();
#pragma unroll
  for (int p = 0; p < 4; ++p) {
    int jj = i0 + p * 8;
    out[(size_t)(c0 + jj) * R + r0 + j] = (u16)s[j][jj];
  }
}

// ---------------- QKV GEMM, pipelined (r8 structure + SXR conflict fix) -----
// K-loop measured (r11, REP=3): 23.2 us/pass ~= 1112 TF. This version: single
// pass, SXR swizzle kills the measured 4-way frag-read bank conflict.
__global__ __launch_bounds__(256, 2) void gemm_qkv(
    const u16* __restrict__ A, const u16* __restrict__ Bt,
    const float* __restrict__ bias,
    u16* __restrict__ q_out, u16* __restrict__ k_out, u16* __restrict__ vt_out) {
  const int K = 1024;
  __shared__ __align__(16) u16 As[4][128 * 32];  // 32 KB
  __shared__ __align__(16) u16 Bs[4][192 * 32];  // 48 KB
  const int tid = threadIdx.x;
  const int lane = tid & 63, wv = tid >> 6;
  const int l16 = lane & 15, quad = lane >> 4;
  const int wm = wv & 1, wn = wv >> 1;
  const int bx = blockIdx.x, by = blockIdx.y;

  const u16* Ab = A + (size_t)by * 128 * K;
  const u16* Bb = Bt + (size_t)bx * 192 * K;

  const int iA0 = tid, iA1 = 256 + tid;
  const int iB0 = tid, iB1 = 256 + tid, iB2 = 512 + tid;
  const u16* sA0 = Ab + (size_t)(iA0 >> 2) * K + (((iA0 & 3) ^ SXR(iA0 >> 2)) << 3);
  const u16* sA1 = Ab + (size_t)(iA1 >> 2) * K + (((iA1 & 3) ^ SXR(iA1 >> 2)) << 3);
  const u16* sB0 = Bb + (size_t)(iB0 >> 2) * K + (((iB0 & 3) ^ SXR(iB0 >> 2)) << 3);
  const u16* sB1 = Bb + (size_t)(iB1 >> 2) * K + (((iB1 & 3) ^ SXR(iB1 >> 2)) << 3);
  const u16* sB2 = Bb + (size_t)(iB2 >> 2) * K + (((iB2 & 3) ^ SXR(iB2 >> 2)) << 3);
  const int dA0 = iA0 << 3, dA1 = iA1 << 3;
  const int dB0 = iB0 << 3, dB1 = iB1 << 3, dB2 = iB2 << 3;

  int aoff[4], boff[6];
#pragma unroll
  for (int mi = 0; mi < 4; ++mi) {
    int r = wm * 64 + mi * 16 + l16;
    aoff[mi] = r * 32 + ((quad ^ SXR(r)) << 3);
  }
#pragma unroll
  for (int ni = 0; ni < 6; ++ni) {
    int r = wn * 96 + ni * 16 + l16;
    boff[ni] = r * 32 + ((quad ^ SXR(r)) << 3);
  }

  const f32x4 fzero = {0.0f, 0.0f, 0.0f, 0.0f};
  f32x4 acc[4][6];
#pragma unroll
  for (int i = 0; i < 4; ++i)
#pragma unroll
    for (int j = 0; j < 6; ++j) acc[i][j] = fzero;

#define STAGE_A(T)                        \
  do {                                    \
    gld16(sA0, &As[T][dA0]);              \
    gld16(sA1, &As[T][dA1]);              \
    sA0 += 32; sA1 += 32;                 \
  } while (0)
#define STAGE_B(T)                        \
  do {                                    \
    gld16(sB0, &Bs[T][dB0]);              \
    gld16(sB1, &Bs[T][dB1]);              \
    gld16(sB2, &Bs[T][dB2]);              \
    sB0 += 32; sB1 += 32; sB2 += 32;      \
  } while (0)
#define VM5 asm volatile("s_waitcnt vmcnt(5)" ::: "memory")
#define VM0 asm volatile("s_waitcnt vmcnt(0)" ::: "memory")

#define GTILE(S, T, DOST, VW)                                              \
  do {                                                                     \
    short8 bb[6];                                                          \
    _Pragma("unroll")                                                      \
    for (int j = 0; j < 6; ++j)                                            \
      bb[j] = *reinterpret_cast<const short8*>(&Bs[S][boff[j]]);           \
    short8 a0 = *reinterpret_cast<const short8*>(&As[S][aoff[0]]);         \
    short8 a1 = *reinterpret_cast<const short8*>(&As[S][aoff[1]]);         \
    if (DOST) { STAGE_A(T); }                                              \
    __builtin_amdgcn_s_barrier();                                          \
    __builtin_amdgcn_s_setprio(1);                                         \
    _Pragma("unroll")                                                      \
    for (int j = 0; j < 6; ++j) {                                          \
      acc[0][j] = __builtin_amdgcn_mfma_f32_16x16x32_bf16(a0, bb[j], acc[0][j], 0, 0, 0); \
      acc[1][j] = __builtin_amdgcn_mfma_f32_16x16x32_bf16(a1, bb[j], acc[1][j], 0, 0, 0); \
    }                                                                      \
    __builtin_amdgcn_s_setprio(0);                                         \
    __builtin_amdgcn_s_barrier();                                          \
    short8 a2 = *reinterpret_cast<const short8*>(&As[S][aoff[2]]);         \
    short8 a3 = *reinterpret_cast<const short8*>(&As[S][aoff[3]]);         \
    if (DOST) { STAGE_B(T); }                                              \
    __builtin_amdgcn_s_barrier();                                          \
    __builtin_amdgcn_s_setprio(1);                                         \
    _Pragma("unroll")                                                      \
    for (int j = 0; j < 6; ++j) {                                          \
      acc[2][j] = __builtin_amdgcn_mfma_f32_16x16x32_bf16(a2, bb[j], acc[2][j], 0, 0, 0); \
      acc[3][j] = __builtin_amdgcn_mfma_f32_16x16x32_bf16(a3, bb[j], acc[3][j], 0, 0, 0); \
    }                                                                      \
    __builtin_amdgcn_s_setprio(0);                                         \
    VW;                                                                    \
    __builtin_amdgcn_s_barrier();                                          \
  } while (0)

  STAGE_A(0); STAGE_B(0);
  STAGE_A(1); STAGE_B(1);
  VM5;
  __builtin_amdgcn_s_barrier();

  for (int kb = 0; kb < 28; kb += 4) {
    GTILE(0, 2, 1, VM5);
    GTILE(1, 3, 1, VM5);
    GTILE(2, 0, 1, VM5);
    GTILE(3, 1, 1, VM5);
  }
  GTILE(0, 2, 1, VM5);
  GTILE(1, 3, 1, VM5);
  GTILE(2, 0, 0, VM0);
  GTILE(3, 1, 0, ((void)0));
#undef GTILE
#undef STAGE_A
#undef STAGE_B

  // epilogue: QKV scatter (verified semantics)
#pragma unroll
  for (int mi = 0; mi < 4; ++mi)
#pragma unroll
    for (int ni = 0; ni < 6; ++ni) {
      int col = bx * 192 + wn * 96 + ni * 16 + l16;
      float bv = bias[col];
      int row0 = by * 128 + wm * 64 + mi * 16 + quad * 4;
      int which = col >> 10, rem = col & 1023;
      int h = rem >> 6, d = rem & 63;
      int b = row0 >> 11, sq0 = row0 & 2047;
      int bh = (b << 4) + h;
      if (which == 2) {
        ushort4 pk;
        pk.x = f2h(acc[mi][ni][0] + bv);
        pk.y = f2h(acc[mi][ni][1] + bv);
        pk.z = f2h(acc[mi][ni][2] + bv);
        pk.w = f2h(acc[mi][ni][3] + bv);
        size_t off = (size_t)bh * 131072 +
                     (((sq0 >> 2) * 16 + (d & 15)) * 16 + ((d >> 4) << 2));
        *reinterpret_cast<ushort4*>(&vt_out[off]) = pk;
      } else {
        size_t base = (size_t)(bh * 2048 + sq0) * 64 + d;
#pragma unroll
        for (int r = 0; r < 4; ++r) {
          float val = acc[mi][ni][r] + bv;
          if (which == 0) q_out[base + r * 64] = f2bf(val * QSCALE);
          else            k_out[base + r * 64] = f2bf(val);
        }
      }
    }
}

// ---------------- out-proj GEMM: exact mirror of the 1112-TF qkv pipeline ---
// C[4096,1024] = A[4096,1024] @ Bt[1024,1024]^T + bias (fp32 out).
// BM=128 x BN=64 x BK=32, 4 waves (2x2), wave = 64x32, acc[4][2].
// 4 LDS slots (48 KB), 2-tile-ahead staging, counted vmcnt(3), raw barriers,
// SXR swizzle. Grid (16,32) = 512 blocks = 2/CU.
__global__ __launch_bounds__(256, 2) void gemm_op(
    const u16* __restrict__ A, const u16* __restrict__ Bt,
    const float* __restrict__ bias, float* __restrict__ c_out) {
  const int K = 1024;
  __shared__ __align__(16) u16 As[4][128 * 32];  // 32 KB
  __shared__ __align__(16) u16 Bs[4][64 * 32];   // 16 KB
  const int tid = threadIdx.x;
  const int lane = tid & 63, wv = tid >> 6;
  const int l16 = lane & 15, quad = lane >> 4;
  const int wm = wv & 1, wn = wv >> 1;
  const int bx = blockIdx.x, by = blockIdx.y;

  const u16* Ab = A + (size_t)by * 128 * K;
  const u16* Bb = Bt + (size_t)bx * 64 * K;

  const int iA0 = tid, iA1 = 256 + tid, iB0 = tid;
  const u16* sA0 = Ab + (size_t)(iA0 >> 2) * K + (((iA0 & 3) ^ SXR(iA0 >> 2)) << 3);
  const u16* sA1 = Ab + (size_t)(iA1 >> 2) * K + (((iA1 & 3) ^ SXR(iA1 >> 2)) << 3);
  const u16* sB0 = Bb + (size_t)(iB0 >> 2) * K + (((iB0 & 3) ^ SXR(iB0 >> 2)) << 3);
  const int dA0 = iA0 << 3, dA1 = iA1 << 3, dB0 = iB0 << 3;

  int aoff[4], boff[2];
#pragma unroll
  for (int mi = 0; mi < 4; ++mi) {
    int r = wm * 64 + mi * 16 + l16;
    aoff[mi] = r * 32 + ((quad ^ SXR(r)) << 3);
  }
#pragma unroll
  for (int ni = 0; ni < 2; ++ni) {
    int r = wn * 32 + ni * 16 + l16;
    boff[ni] = r * 32 + ((quad ^ SXR(r)) << 3);
  }

  const f32x4 fzero = {0.0f, 0.0f, 0.0f, 0.0f};
  f32x4 acc[4][2];
#pragma unroll
  for (int i = 0; i < 4; ++i)
#pragma unroll
    for (int j = 0; j < 2; ++j) acc[i][j] = fzero;

#define STAGE_A(T)                        \
  do {                                    \
    gld16(sA0, &As[T][dA0]);              \
    gld16(sA1, &As[T][dA1]);              \
    sA0 += 32; sA1 += 32;                 \
  } while (0)
#define STAGE_B(T)                        \
  do {                                    \
    gld16(sB0, &Bs[T][dB0]);              \
    sB0 += 32;                            \
  } while (0)
#define VM3 asm volatile("s_waitcnt vmcnt(3)" ::: "memory")
#define VM0b asm volatile("s_waitcnt vmcnt(0)" ::: "memory")

#define OTILE(S, T, DOST, VW)                                              \
  do {                                                                     \
    short8 b0 = *reinterpret_cast<const short8*>(&Bs[S][boff[0]]);         \
    short8 b1 = *reinterpret_cast<const short8*>(&Bs[S][boff[1]]);         \
    short8 a0 = *reinterpret_cast<const short8*>(&As[S][aoff[0]]);         \
    short8 a1 = *reinterpret_cast<const short8*>(&As[S][aoff[1]]);         \
    if (DOST) { STAGE_A(T); }                                              \
    __builtin_amdgcn_s_barrier();                                          \
    __builtin_amdgcn_s_setprio(1);                                         \
    acc[0][0] = __builtin_amdgcn_mfma_f32_16x16x32_bf16(a0, b0, acc[0][0], 0, 0, 0); \
    acc[0][1] = __builtin_amdgcn_mfma_f32_16x16x32_bf16(a0, b1, acc[0][1], 0, 0, 0); \
    acc[1][0] = __builtin_amdgcn_mfma_f32_16x16x32_bf16(a1, b0, acc[1][0], 0, 0, 0); \
    acc[1][1] = __builtin_amdgcn_mfma_f32_16x16x32_bf16(a1, b1, acc[1][1], 0, 0, 0); \
    __builtin_amdgcn_s_setprio(0);                                         \
    __builtin_amdgcn_s_barrier();                                          \
    short8 a2 = *reinterpret_cast<const short8*>(&As[S][aoff[2]]);         \
    short8 a3 = *reinterpret_cast<const short8*>(&As[S][aoff[3]]);         \
    if (DOST) { STAGE_B(T); }                                              \
    __builtin_amdgcn_s_barrier();                                          \
    __builtin_amdgcn_s_setprio(1);                                         \
    acc[2][0] = __builtin_amdgcn_mfma_f32_16x16x32_bf16(a2, b0, acc[2][0], 0, 0, 0); \
    acc[2][1] = __builtin_amdgcn_mfma_f32_16x16x32_bf16(a2, b1, acc[2][1], 0, 0, 0); \
    acc[3][0] = __builtin_amdgcn_mfma_f32_16x16x32_bf16(a3, b0, acc[3][0], 0, 0, 0); \
    acc[3][1] = __builtin_amdgcn_mfma_f32_16x16x32_bf16(a3, b1, acc[3][1], 0, 0, 0); \
    __builtin_amdgcn_s_setprio(0);                                         \
    VW;                                                                    \
    __builtin_amdgcn_s_barrier();                                          \
  } while (0)

  STAGE_A(0); STAGE_B(0);
  STAGE_A(1); STAGE_B(1);
  VM3;
  __builtin_amdgcn_s_barrier();

  for (int kb = 0; kb < 28; kb += 4) {
    OTILE(0, 2, 1, VM3);
    OTILE(1, 3, 1, VM3);
    OTILE(2, 0, 1, VM3);
    OTILE(3, 1, 1, VM3);
  }
  OTILE(0, 2, 1, VM3);
  OTILE(1, 3, 1, VM3);
  OTILE(2, 0, 0, VM0b);
  OTILE(3, 1, 0, ((void)0));
#undef OTILE
#undef STAGE_A
#undef STAGE_B

  // epilogue: coalesced fp32
#pragma unroll
  for (int mi = 0; mi < 4; ++mi)
#pragma unroll
    for (int ni = 0; ni < 2; ++ni) {
      int col = bx * 64 + wn * 32 + ni * 16 + l16;
      float bv = bias[col];
      int row0 = by * 128 + wm * 64 + mi * 16 + quad * 4;
#pragma unroll
      for (int r = 0; r < 4; ++r)
        c_out[(size_t)(row0 + r) * 1024 + col] = acc[mi][ni][r] + bv;
    }
}

// ---------------- flash attention (r7 version: best measured, 51.2 us) ------
__global__ __launch_bounds__(256, 4) void attn(
    const u16* __restrict__ q_buf, const u16* __restrict__ k_buf,
    const u16* __restrict__ vt_buf, u16* __restrict__ o_buf) {
  __shared__ __align__(16) u16 Ks[2][4096];
  __shared__ __align__(16) u16 Vs[2][4096];

  const int tid = threadIdx.x;
  const int lane = tid & 63, w = tid >> 6;
  const int l16 = lane & 15, quad = lane >> 4;
  const int bh = blockIdx.x, q0 = blockIdx.y * 64;

  const u16* qg = q_buf + (size_t)bh * 131072 + (q0 + w * 16) * 64;
  const u16* kg = k_buf + (size_t)bh * 131072;
  const u16* vg = vt_buf + (size_t)bh * 131072;

  short8 qb[2];
#pragma unroll
  for (int kk = 0; kk < 2; ++kk)
    qb[kk] = *reinterpret_cast<const short8*>(qg + l16 * 64 + kk * 32 + quad * 8);

  const int idA = tid, idB = 256 + tid;
  const u16* ksA = kg + (idA >> 3) * 64 + (((idA & 7) ^ ((idA >> 3) & 7)) << 3);
  const u16* ksB = kg + (idB >> 3) * 64 + (((idB & 7) ^ ((idB >> 3) & 7)) << 3);
  const u16* vsA = vg + ((idA ^ ((idA >> 4) & 1)) << 3);
  const u16* vsB = vg + ((idB ^ ((idB >> 4) & 1)) << 3);
  const int ldA = idA << 3, ldB = idB << 3;

  int k0o[4], k1o[4], v0o[4], v1o[4];
#pragma unroll
  for (int t = 0; t < 4; ++t) {
    int rr = t * 16 + l16;
    k0o[t] = rr * 64 + ((quad ^ (rr & 7)) << 3);
    k1o[t] = rr * 64 + (((4 + quad) ^ (rr & 7)) << 3);
    int gb = (t * 4 + quad) * 32 + l16 * 2;
    int sw = (l16 >> 3) & 1;
    v0o[t] = (gb + sw) << 3;
    v1o[t] = (gb + (sw ^ 1)) << 3;
  }

  const f32x4 fzero = {0.0f, 0.0f, 0.0f, 0.0f};
  f32x4 o_acc[4];
  float l_acc = 0.f;
#pragma unroll
  for (int nd = 0; nd < 4; ++nd) o_acc[nd] = fzero;

#define STAGE(BUF)                           \
  do {                                       \
    gld16(ksA, &Ks[BUF][ldA]);               \
    gld16(ksB, &Ks[BUF][ldB]);               \
    gld16(vsA, &Vs[BUF][ldA]);               \
    gld16(vsB, &Vs[BUF][ldB]);               \
    ksA += 4096; ksB += 4096;                \
    vsA += 4096; vsB += 4096;                \
  } while (0)

#define TILE(BUF)                                                         \
  do {                                                                    \
    _Pragma("unroll")                                                     \
    for (int t = 0; t < 4; ++t) {                                         \
      short8 k0f = *reinterpret_cast<const short8*>(&Ks[BUF][k0o[t]]);    \
      short8 k1f = *reinterpret_cast<const short8*>(&Ks[BUF][k1o[t]]);    \
      half8 v0 = *reinterpret_cast<const half8*>(&Vs[BUF][v0o[t]]);       \
      half8 v1 = *reinterpret_cast<const half8*>(&Vs[BUF][v1o[t]]);       \
      half4 vb0 = __builtin_shufflevector(v0, v0, 0, 1, 2, 3);            \
      half4 vb1 = __builtin_shufflevector(v0, v0, 4, 5, 6, 7);            \
      half4 vb2 = __builtin_shufflevector(v1, v1, 0, 1, 2, 3);            \
      half4 vb3 = __builtin_shufflevector(v1, v1, 4, 5, 6, 7);            \
      __builtin_amdgcn_s_setprio(1);                                      \
      f32x4 s = __builtin_amdgcn_mfma_f32_16x16x32_bf16(k0f, qb[0], fzero, 0, 0, 0); \
      s = __builtin_amdgcn_mfma_f32_16x16x32_bf16(k1f, qb[1], s, 0, 0, 0);\
      __builtin_amdgcn_s_setprio(0);                                      \
      float p0 = __builtin_amdgcn_exp2f(s[0]);                            \
      float p1 = __builtin_amdgcn_exp2f(s[1]);                            \
      float p2 = __builtin_amdgcn_exp2f(s[2]);                            \
      float p3 = __builtin_amdgcn_exp2f(s[3]);                            \
      l_acc += (p0 + p1) + (p2 + p3);                                     \
      half4 pa;                                                           \
      pa[0] = (_Float16)p0; pa[1] = (_Float16)p1;                         \
      pa[2] = (_Float16)p2; pa[3] = (_Float16)p3;                         \
      __builtin_amdgcn_s_setprio(1);                                      \
      o_acc[0] = __builtin_amdgcn_mfma_f32_16x16x16f16(pa, vb0, o_acc[0], 0, 0, 0); \
      o_acc[1] = __builtin_amdgcn_mfma_f32_16x16x16f16(pa, vb1, o_acc[1], 0, 0, 0); \
      o_acc[2] = __builtin_amdgcn_mfma_f32_16x16x16f16(pa, vb2, o_acc[2], 0, 0, 0); \
      o_acc[3] = __builtin_amdgcn_mfma_f32_16x16x16f16(pa, vb3, o_acc[3], 0, 0, 0); \
      __builtin_amdgcn_s_setprio(0);                                      \
    }                                                                     \
  } while (0)

  STAGE(0);
  __syncthreads();

  for (int i = 0; i < 32; i += 2) {
    if (i + 1 < 32) STAGE(1);
    TILE(0);
    __syncthreads();
    if (i + 2 < 32) STAGE(0);
    TILE(1);
    __syncthreads();
  }
#undef STAGE
#undef TILE

  l_acc += __shfl_xor(l_acc, 16, 64);
  l_acc += __shfl_xor(l_acc, 32, 64);

  const int b = bh >> 4, h = bh & 15;
  float lv[4];
#pragma unroll
  for (int r = 0; r < 4; ++r)
    lv[r] = __shfl(l_acc, quad * 4 + r, 64);
#pragma unroll
  for (int nd = 0; nd < 4; ++nd) {
#pragma unroll
    for (int r = 0; r < 4; ++r) {
      int sq = q0 + w * 16 + quad * 4 + r;
      o_buf[(size_t)(b * 2048 + sq) * 1024 + h * 64 + nd * 16 + l16] =
          f2bf(o_acc[nd][r] / lv[r]);
    }
  }
}

extern "C" void kernel_launch(void* const* d_in, const int* in_sizes, int n_in,
                              void* d_out, int out_size, void* d_ws, size_t ws_size,
                              hipStream_t stream) {
  (void)in_sizes; (void)n_in; (void)out_size; (void)ws_size;
  const float* x     = (const float*)d_in[0];
  const float* W_qkv = (const float*)d_in[1];
  const float* b_qkv = (const float*)d_in[2];
  const float* W_out = (const float*)d_in[3];
  const float* b_out = (const float*)d_in[4];
  float* out = (float*)d_out;

  // workspace layout (48 MB total)
  char* ws = (char*)d_ws;
  u16* x_bf   = (u16*)(ws);              //  8 MB  [4096][1024] bf16
  u16* wqkv_t = (u16*)(ws + 8388608);    //  6 MB  [3072][1024] bf16
  u16* wout_t = (u16*)(ws + 14680064);   //  2 MB  [1024][1024] bf16
  u16* q_buf  = (u16*)(ws + 16777216);   //  8 MB  [32][2048][64] bf16
  u16* k_buf  = (u16*)(ws + 25165824);   //  8 MB  [32][2048][64] bf16
  u16* vt_buf = (u16*)(ws + 33554432);   //  8 MB  [32] V-frag fp16 layout
  u16* o_bf   = (u16*)(ws + 41943040);   //  8 MB  [4096][1024] bf16

  prep<<<8192, 256, 0, stream>>>(x, x_bf, W_qkv, wqkv_t, W_out, wout_t);
  gemm_qkv<<<dim3(16, 32), 256, 0, stream>>>(x_bf, wqkv_t, b_qkv,
                                             q_buf, k_buf, vt_buf);
  attn<<<dim3(32, 32), 256, 0, stream>>>(q_buf, k_buf, vt_buf, o_bf);
  gemm_op<<<dim3(16, 32), 256, 0, stream>>>(o_bf, wout_t, b_out, out);
}

// Round 13
// 181.811 us; speedup vs baseline: 1.2911x; 1.0138x over previous
//
#include <hip/hip_runtime.h>

typedef unsigned short u16;
typedef unsigned int   u32;

using short8 = __attribute__((ext_vector_type(8))) short;
using f32x4  = __attribute__((ext_vector_type(4))) float;
using half4  = __attribute__((ext_vector_type(4))) _Float16;
using half8  = __attribute__((ext_vector_type(8))) _Float16;

// SCALE * log2(e) folded into q at the QKV epilogue
#define QSCALE 0.18033688011112042f
// conflict-free chunk swizzle (r12-verified): rows r..r+12 -> 4 distinct slots
#define SXR(r) ((((r) ^ ((r) >> 2))) & 3)

__device__ __forceinline__ u16 f2bf(float f) {
  u32 u = __float_as_uint(f);
  return (u16)((u + 0x8000u) >> 16);
}
__device__ __forceinline__ u16 f2h(float f) {
  _Float16 h = (_Float16)f;
  return __builtin_bit_cast(u16, h);
}

// async global->LDS DMA, 16B per lane; lds dest = wave-uniform base + lane*16
__device__ __forceinline__ void gld16(const u16* g, u16* l) {
  __builtin_amdgcn_global_load_lds(
      (const __attribute__((address_space(1))) unsigned int*)g,
      (__attribute__((address_space(3))) unsigned int*)l, 16, 0, 0);
}

// ---------------- fused preprocessing (r12 version, unchanged) --------------
__global__ __launch_bounds__(256) void prep(
    const float* __restrict__ x, u16* __restrict__ x_bf,
    const float* __restrict__ Wq, u16* __restrict__ wq_t,
    const float* __restrict__ Wo, u16* __restrict__ wo_t) {
  __shared__ u32 s[32][33];
  const int bid = blockIdx.x, tid = threadIdx.x;
  if (bid < 4096) {
    int idx = bid * 256 + tid;
    float4 v = reinterpret_cast<const float4*>(x)[idx];
    ushort4 o;
    o.x = f2bf(v.x); o.y = f2bf(v.y); o.z = f2bf(v.z); o.w = f2bf(v.w);
    reinterpret_cast<ushort4*>(x_bf)[idx] = o;
    return;
  }
  const float* in; u16* out; int R, C, bx, by;
  if (bid < 7168) { int b = bid - 4096; in = Wq; out = wq_t; R = 1024; C = 3072; bx = b % 96; by = b / 96; }
  else            { int b = bid - 7168; in = Wo; out = wo_t; R = 1024; C = 1024; bx = b % 32; by = b / 32; }
  int c0 = bx * 32, r0 = by * 32;
  int j = tid & 31, i0 = tid >> 5;
#pragma unroll
  for (int p = 0; p < 4; ++p) {
    int i = i0 + p * 8;
    s[i][j] = f2bf(in[(size_t)(r0 + i) * C + c0 + j]);
  }
  __syncthreads();
#pragma unroll
  for (int p = 0; p < 4; ++p) {
    int jj = i0 + p * 8;
    out[(size_t)(c0 + jj) * R + r0 + j] = (u16)s[j][jj];
  }
}

// ---------------- QKV GEMM: 1-barrier/tile + XCD-chunked ---------------------
// r11 measured: K-loop 23.2us (L2-hot), 4 barriers/tile = 128 crossings.
// Hazard analysis: ONE barrier/tile suffices (slot restage distance 4 tiles;
// frag ds_reads consumed by same-tile MFMAs; vmcnt(5) before the barrier
// guarantees tile kt+1's DMA landed). XCD 2D chunking: 8by x 8bx per XCD ->
// 5MB working set vs 8.8MB linear (r11 FETCH 36MB vs 14MB unique).
__global__ __launch_bounds__(256, 2) void gemm_qkv(
    const u16* __restrict__ A, const u16* __restrict__ Bt,
    const float* __restrict__ bias,
    u16* __restrict__ q_out, u16* __restrict__ k_out, u16* __restrict__ vt_out) {
  const int K = 1024;
  __shared__ __align__(16) u16 As[4][128 * 32];  // 32 KB
  __shared__ __align__(16) u16 Bs[4][192 * 32];  // 48 KB
  const int tid = threadIdx.x;
  const int lane = tid & 63, wv = tid >> 6;
  const int l16 = lane & 15, quad = lane >> 4;
  const int wm = wv & 1, wn = wv >> 1;

  // XCD 2D chunking: lin -> (xcd, idx); XCD x owns 8by x 8bx block
  const int lin = blockIdx.y * 16 + blockIdx.x;
  const int xcd = lin & 7, idx = lin >> 3;
  const int bx = (xcd & 1) * 8 + (idx & 7);
  const int by = (xcd >> 1) * 8 + (idx >> 3);

  const u16* Ab = A + (size_t)by * 128 * K;
  const u16* Bb = Bt + (size_t)bx * 192 * K;

  const int iA0 = tid, iA1 = 256 + tid;
  const int iB0 = tid, iB1 = 256 + tid, iB2 = 512 + tid;
  const u16* sA0 = Ab + (size_t)(iA0 >> 2) * K + (((iA0 & 3) ^ SXR(iA0 >> 2)) << 3);
  const u16* sA1 = Ab + (size_t)(iA1 >> 2) * K + (((iA1 & 3) ^ SXR(iA1 >> 2)) << 3);
  const u16* sB0 = Bb + (size_t)(iB0 >> 2) * K + (((iB0 & 3) ^ SXR(iB0 >> 2)) << 3);
  const u16* sB1 = Bb + (size_t)(iB1 >> 2) * K + (((iB1 & 3) ^ SXR(iB1 >> 2)) << 3);
  const u16* sB2 = Bb + (size_t)(iB2 >> 2) * K + (((iB2 & 3) ^ SXR(iB2 >> 2)) << 3);
  const int dA0 = iA0 << 3, dA1 = iA1 << 3;
  const int dB0 = iB0 << 3, dB1 = iB1 << 3, dB2 = iB2 << 3;

  int aoff[4], boff[6];
#pragma unroll
  for (int mi = 0; mi < 4; ++mi) {
    int r = wm * 64 + mi * 16 + l16;
    aoff[mi] = r * 32 + ((quad ^ SXR(r)) << 3);
  }
#pragma unroll
  for (int ni = 0; ni < 6; ++ni) {
    int r = wn * 96 + ni * 16 + l16;
    boff[ni] = r * 32 + ((quad ^ SXR(r)) << 3);
  }

  const f32x4 fzero = {0.0f, 0.0f, 0.0f, 0.0f};
  f32x4 acc[4][6];
#pragma unroll
  for (int i = 0; i < 4; ++i)
#pragma unroll
    for (int j = 0; j < 6; ++j) acc[i][j] = fzero;

#define STAGE_A(T)                        \
  do {                                    \
    gld16(sA0, &As[T][dA0]);              \
    gld16(sA1, &As[T][dA1]);              \
    sA0 += 32; sA1 += 32;                 \
  } while (0)
#define STAGE_B(T)                        \
  do {                                    \
    gld16(sB0, &Bs[T][dB0]);              \
    gld16(sB1, &Bs[T][dB1]);              \
    gld16(sB2, &Bs[T][dB2]);              \
    sB0 += 32; sB1 += 32; sB2 += 32;      \
  } while (0)
#define VM5 asm volatile("s_waitcnt vmcnt(5)" ::: "memory")
#define VM0 asm volatile("s_waitcnt vmcnt(0)" ::: "memory")

// one barrier per tile: frags read -> stage kt+2 -> 24 MFMA -> vmcnt(5)
// (kt+1's DMA landed; kt+2's 5 stay in flight) -> s_barrier
#define GTILE(S, T, DOST, VW)                                              \
  do {                                                                     \
    short8 bb[6];                                                          \
    _Pragma("unroll")                                                      \
    for (int j = 0; j < 6; ++j)                                            \
      bb[j] = *reinterpret_cast<const short8*>(&Bs[S][boff[j]]);           \
    short8 a0 = *reinterpret_cast<const short8*>(&As[S][aoff[0]]);         \
    short8 a1 = *reinterpret_cast<const short8*>(&As[S][aoff[1]]);         \
    short8 a2 = *reinterpret_cast<const short8*>(&As[S][aoff[2]]);         \
    short8 a3 = *reinterpret_cast<const short8*>(&As[S][aoff[3]]);         \
    if (DOST) { STAGE_A(T); STAGE_B(T); }                                  \
    __builtin_amdgcn_s_setprio(1);                                         \
    _Pragma("unroll")                                                      \
    for (int j = 0; j < 6; ++j) {                                          \
      acc[0][j] = __builtin_amdgcn_mfma_f32_16x16x32_bf16(a0, bb[j], acc[0][j], 0, 0, 0); \
      acc[1][j] = __builtin_amdgcn_mfma_f32_16x16x32_bf16(a1, bb[j], acc[1][j], 0, 0, 0); \
      acc[2][j] = __builtin_amdgcn_mfma_f32_16x16x32_bf16(a2, bb[j], acc[2][j], 0, 0, 0); \
      acc[3][j] = __builtin_amdgcn_mfma_f32_16x16x32_bf16(a3, bb[j], acc[3][j], 0, 0, 0); \
    }                                                                      \
    __builtin_amdgcn_s_setprio(0);                                         \
    VW;                                                                    \
    __builtin_amdgcn_s_barrier();                                          \
  } while (0)

  STAGE_A(0); STAGE_B(0);
  STAGE_A(1); STAGE_B(1);
  VM5;
  __builtin_amdgcn_s_barrier();

  for (int kb = 0; kb < 28; kb += 4) {
    GTILE(0, 2, 1, VM5);
    GTILE(1, 3, 1, VM5);
    GTILE(2, 0, 1, VM5);
    GTILE(3, 1, 1, VM5);
  }
  GTILE(0, 2, 1, VM5);        // kt=28 stages tile 30
  GTILE(1, 3, 1, VM5);        // kt=29 stages tile 31
  GTILE(2, 0, 0, VM0);        // kt=30 waits tile 31
  GTILE(3, 1, 0, ((void)0));  // kt=31
#undef GTILE
#undef STAGE_A
#undef STAGE_B

  // epilogue: QKV scatter (verified semantics)
#pragma unroll
  for (int mi = 0; mi < 4; ++mi)
#pragma unroll
    for (int ni = 0; ni < 6; ++ni) {
      int col = bx * 192 + wn * 96 + ni * 16 + l16;
      float bv = bias[col];
      int row0 = by * 128 + wm * 64 + mi * 16 + quad * 4;
      int which = col >> 10, rem = col & 1023;
      int h = rem >> 6, d = rem & 63;
      int b = row0 >> 11, sq0 = row0 & 2047;
      int bh = (b << 4) + h;
      if (which == 2) {
        ushort4 pk;
        pk.x = f2h(acc[mi][ni][0] + bv);
        pk.y = f2h(acc[mi][ni][1] + bv);
        pk.z = f2h(acc[mi][ni][2] + bv);
        pk.w = f2h(acc[mi][ni][3] + bv);
        size_t off = (size_t)bh * 131072 +
                     (((sq0 >> 2) * 16 + (d & 15)) * 16 + ((d >> 4) << 2));
        *reinterpret_cast<ushort4*>(&vt_out[off]) = pk;
      } else {
        size_t base = (size_t)(bh * 2048 + sq0) * 64 + d;
#pragma unroll
        for (int r = 0; r < 4; ++r) {
          float val = acc[mi][ni][r] + bv;
          if (which == 0) q_out[base + r * 64] = f2bf(val * QSCALE);
          else            k_out[base + r * 64] = f2bf(val);
        }
      }
    }
}

// ---------------- out-proj GEMM: 1-barrier/tile + XCD-chunked ----------------
__global__ __launch_bounds__(256, 2) void gemm_op(
    const u16* __restrict__ A, const u16* __restrict__ Bt,
    const float* __restrict__ bias, float* __restrict__ c_out) {
  const int K = 1024;
  __shared__ __align__(16) u16 As[4][128 * 32];  // 32 KB
  __shared__ __align__(16) u16 Bs[4][64 * 32];   // 16 KB
  const int tid = threadIdx.x;
  const int lane = tid & 63, wv = tid >> 6;
  const int l16 = lane & 15, quad = lane >> 4;
  const int wm = wv & 1, wn = wv >> 1;

  const int lin = blockIdx.y * 16 + blockIdx.x;
  const int xcd = lin & 7, idx = lin >> 3;
  const int bx = (xcd & 1) * 8 + (idx & 7);
  const int by = (xcd >> 1) * 8 + (idx >> 3);

  const u16* Ab = A + (size_t)by * 128 * K;
  const u16* Bb = Bt + (size_t)bx * 64 * K;

  const int iA0 = tid, iA1 = 256 + tid, iB0 = tid;
  const u16* sA0 = Ab + (size_t)(iA0 >> 2) * K + (((iA0 & 3) ^ SXR(iA0 >> 2)) << 3);
  const u16* sA1 = Ab + (size_t)(iA1 >> 2) * K + (((iA1 & 3) ^ SXR(iA1 >> 2)) << 3);
  const u16* sB0 = Bb + (size_t)(iB0 >> 2) * K + (((iB0 & 3) ^ SXR(iB0 >> 2)) << 3);
  const int dA0 = iA0 << 3, dA1 = iA1 << 3, dB0 = iB0 << 3;

  int aoff[4], boff[2];
#pragma unroll
  for (int mi = 0; mi < 4; ++mi) {
    int r = wm * 64 + mi * 16 + l16;
    aoff[mi] = r * 32 + ((quad ^ SXR(r)) << 3);
  }
#pragma unroll
  for (int ni = 0; ni < 2; ++ni) {
    int r = wn * 32 + ni * 16 + l16;
    boff[ni] = r * 32 + ((quad ^ SXR(r)) << 3);
  }

  const f32x4 fzero = {0.0f, 0.0f, 0.0f, 0.0f};
  f32x4 acc[4][2];
#pragma unroll
  for (int i = 0; i < 4; ++i)
#pragma unroll
    for (int j = 0; j < 2; ++j) acc[i][j] = fzero;

#define STAGE_A(T)                        \
  do {                                    \
    gld16(sA0, &As[T][dA0]);              \
    gld16(sA1, &As[T][dA1]);              \
    sA0 += 32; sA1 += 32;                 \
  } while (0)
#define STAGE_B(T)                        \
  do {                                    \
    gld16(sB0, &Bs[T][dB0]);              \
    sB0 += 32;                            \
  } while (0)
#define VM3 asm volatile("s_waitcnt vmcnt(3)" ::: "memory")
#define VM0b asm volatile("s_waitcnt vmcnt(0)" ::: "memory")

#define OTILE(S, T, DOST, VW)                                              \
  do {                                                                     \
    short8 b0 = *reinterpret_cast<const short8*>(&Bs[S][boff[0]]);         \
    short8 b1 = *reinterpret_cast<const short8*>(&Bs[S][boff[1]]);         \
    short8 a0 = *reinterpret_cast<const short8*>(&As[S][aoff[0]]);         \
    short8 a1 = *reinterpret_cast<const short8*>(&As[S][aoff[1]]);         \
    short8 a2 = *reinterpret_cast<const short8*>(&As[S][aoff[2]]);         \
    short8 a3 = *reinterpret_cast<const short8*>(&As[S][aoff[3]]);         \
    if (DOST) { STAGE_A(T); STAGE_B(T); }                                  \
    __builtin_amdgcn_s_setprio(1);                                         \
    acc[0][0] = __builtin_amdgcn_mfma_f32_16x16x32_bf16(a0, b0, acc[0][0], 0, 0, 0); \
    acc[0][1] = __builtin_amdgcn_mfma_f32_16x16x32_bf16(a0, b1, acc[0][1], 0, 0, 0); \
    acc[1][0] = __builtin_amdgcn_mfma_f32_16x16x32_bf16(a1, b0, acc[1][0], 0, 0, 0); \
    acc[1][1] = __builtin_amdgcn_mfma_f32_16x16x32_bf16(a1, b1, acc[1][1], 0, 0, 0); \
    acc[2][0] = __builtin_amdgcn_mfma_f32_16x16x32_bf16(a2, b0, acc[2][0], 0, 0, 0); \
    acc[2][1] = __builtin_amdgcn_mfma_f32_16x16x32_bf16(a2, b1, acc[2][1], 0, 0, 0); \
    acc[3][0] = __builtin_amdgcn_mfma_f32_16x16x32_bf16(a3, b0, acc[3][0], 0, 0, 0); \
    acc[3][1] = __builtin_amdgcn_mfma_f32_16x16x32_bf16(a3, b1, acc[3][1], 0, 0, 0); \
    __builtin_amdgcn_s_setprio(0);                                         \
    VW;                                                                    \
    __builtin_amdgcn_s_barrier();                                          \
  } while (0)

  STAGE_A(0); STAGE_B(0);
  STAGE_A(1); STAGE_B(1);
  VM3;
  __builtin_amdgcn_s_barrier();

  for (int kb = 0; kb < 28; kb += 4) {
    OTILE(0, 2, 1, VM3);
    OTILE(1, 3, 1, VM3);
    OTILE(2, 0, 1, VM3);
    OTILE(3, 1, 1, VM3);
  }
  OTILE(0, 2, 1, VM3);
  OTILE(1, 3, 1, VM3);
  OTILE(2, 0, 0, VM0b);
  OTILE(3, 1, 0, ((void)0));
#undef OTILE
#undef STAGE_A
#undef STAGE_B

  // epilogue: coalesced fp32
#pragma unroll
  for (int mi = 0; mi < 4; ++mi)
#pragma unroll
    for (int ni = 0; ni < 2; ++ni) {
      int col = bx * 64 + wn * 32 + ni * 16 + l16;
      float bv = bias[col];
      int row0 = by * 128 + wm * 64 + mi * 16 + quad * 4;
#pragma unroll
      for (int r = 0; r < 4; ++r)
        c_out[(size_t)(row0 + r) * 1024 + col] = acc[mi][ni][r] + bv;
    }
}

// ---------------- flash attention (r7 version: best measured, 51.2 us) ------
__global__ __launch_bounds__(256, 4) void attn(
    const u16* __restrict__ q_buf, const u16* __restrict__ k_buf,
    const u16* __restrict__ vt_buf, u16* __restrict__ o_buf) {
  __shared__ __align__(16) u16 Ks[2][4096];
  __shared__ __align__(16) u16 Vs[2][4096];

  const int tid = threadIdx.x;
  const int lane = tid & 63, w = tid >> 6;
  const int l16 = lane & 15, quad = lane >> 4;
  const int bh = blockIdx.x, q0 = blockIdx.y * 64;

  const u16* qg = q_buf + (size_t)bh * 131072 + (q0 + w * 16) * 64;
  const u16* kg = k_buf + (size_t)bh * 131072;
  const u16* vg = vt_buf + (size_t)bh * 131072;

  short8 qb[2];
#pragma unroll
  for (int kk = 0; kk < 2; ++kk)
    qb[kk] = *reinterpret_cast<const short8*>(qg + l16 * 64 + kk * 32 + quad * 8);

  const int idA = tid, idB = 256 + tid;
  const u16* ksA = kg + (idA >> 3) * 64 + (((idA & 7) ^ ((idA >> 3) & 7)) << 3);
  const u16* ksB = kg + (idB >> 3) * 64 + (((idB & 7) ^ ((idB >> 3) & 7)) << 3);
  const u16* vsA = vg + ((idA ^ ((idA >> 4) & 1)) << 3);
  const u16* vsB = vg + ((idB ^ ((idB >> 4) & 1)) << 3);
  const int ldA = idA << 3, ldB = idB << 3;

  int k0o[4], k1o[4], v0o[4], v1o[4];
#pragma unroll
  for (int t = 0; t < 4; ++t) {
    int rr = t * 16 + l16;
    k0o[t] = rr * 64 + ((quad ^ (rr & 7)) << 3);
    k1o[t] = rr * 64 + (((4 + quad) ^ (rr & 7)) << 3);
    int gb = (t * 4 + quad) * 32 + l16 * 2;
    int sw = (l16 >> 3) & 1;
    v0o[t] = (gb + sw) << 3;
    v1o[t] = (gb + (sw ^ 1)) << 3;
  }

  const f32x4 fzero = {0.0f, 0.0f, 0.0f, 0.0f};
  f32x4 o_acc[4];
  float l_acc = 0.f;
#pragma unroll
  for (int nd = 0; nd < 4; ++nd) o_acc[nd] = fzero;

#define STAGE(BUF)                           \
  do {                                       \
    gld16(ksA, &Ks[BUF][ldA]);               \
    gld16(ksB, &Ks[BUF][ldB]);               \
    gld16(vsA, &Vs[BUF][ldA]);               \
    gld16(vsB, &Vs[BUF][ldB]);               \
    ksA += 4096; ksB += 4096;                \
    vsA += 4096; vsB += 4096;                \
  } while (0)

#define TILE(BUF)                                                         \
  do {                                                                    \
    _Pragma("unroll")                                                     \
    for (int t = 0; t < 4; ++t) {                                         \
      short8 k0f = *reinterpret_cast<const short8*>(&Ks[BUF][k0o[t]]);    \
      short8 k1f = *reinterpret_cast<const short8*>(&Ks[BUF][k1o[t]]);    \
      half8 v0 = *reinterpret_cast<const half8*>(&Vs[BUF][v0o[t]]);       \
      half8 v1 = *reinterpret_cast<const half8*>(&Vs[BUF][v1o[t]]);       \
      half4 vb0 = __builtin_shufflevector(v0, v0, 0, 1, 2, 3);            \
      half4 vb1 = __builtin_shufflevector(v0, v0, 4, 5, 6, 7);            \
      half4 vb2 = __builtin_shufflevector(v1, v1, 0, 1, 2, 3);            \
      half4 vb3 = __builtin_shufflevector(v1, v1, 4, 5, 6, 7);            \
      __builtin_amdgcn_s_setprio(1);                                      \
      f32x4 s = __builtin_amdgcn_mfma_f32_16x16x32_bf16(k0f, qb[0], fzero, 0, 0, 0); \
      s = __builtin_amdgcn_mfma_f32_16x16x32_bf16(k1f, qb[1], s, 0, 0, 0);\
      __builtin_amdgcn_s_setprio(0);                                      \
      float p0 = __builtin_amdgcn_exp2f(s[0]);                            \
      float p1 = __builtin_amdgcn_exp2f(s[1]);                            \
      float p2 = __builtin_amdgcn_exp2f(s[2]);                            \
      float p3 = __builtin_amdgcn_exp2f(s[3]);                            \
      l_acc += (p0 + p1) + (p2 + p3);                                     \
      half4 pa;                                                           \
      pa[0] = (_Float16)p0; pa[1] = (_Float16)p1;                         \
      pa[2] = (_Float16)p2; pa[3] = (_Float16)p3;                         \
      __builtin_amdgcn_s_setprio(1);                                      \
      o_acc[0] = __builtin_amdgcn_mfma_f32_16x16x16f16(pa, vb0, o_acc[0], 0, 0, 0); \
      o_acc[1] = __builtin_amdgcn_mfma_f32_16x16x16f16(pa, vb1, o_acc[1], 0, 0, 0); \
      o_acc[2] = __builtin_amdgcn_mfma_f32_16x16x16f16(pa, vb2, o_acc[2], 0, 0, 0); \
      o_acc[3] = __builtin_amdgcn_mfma_f32_16x16x16f16(pa, vb3, o_acc[3], 0, 0, 0); \
      __builtin_amdgcn_s_setprio(0);                                      \
    }                                                                     \
  } while (0)

  STAGE(0);
  __syncthreads();

  for (int i = 0; i < 32; i += 2) {
    if (i + 1 < 32) STAGE(1);
    TILE(0);
    __syncthreads();
    if (i + 2 < 32) STAGE(0);
    TILE(1);
    __syncthreads();
  }
#undef STAGE
#undef TILE

  l_acc += __shfl_xor(l_acc, 16, 64);
  l_acc += __shfl_xor(l_acc, 32, 64);

  const int b = bh >> 4, h = bh & 15;
  float lv[4];
#pragma unroll
  for (int r = 0; r < 4; ++r)
    lv[r] = __shfl(l_acc, quad * 4 + r, 64);
#pragma unroll
  for (int nd = 0; nd < 4; ++nd) {
#pragma unroll
    for (int r = 0; r < 4; ++r) {
      int sq = q0 + w * 16 + quad * 4 + r;
      o_buf[(size_t)(b * 2048 + sq) * 1024 + h * 64 + nd * 16 + l16] =
          f2bf(o_acc[nd][r] / lv[r]);
    }
  }
}

extern "C" void kernel_launch(void* const* d_in, const int* in_sizes, int n_in,
                              void* d_out, int out_size, void* d_ws, size_t ws_size,
                              hipStream_t stream) {
  (void)in_sizes; (void)n_in; (void)out_size; (void)ws_size;
  const float* x     = (const float*)d_in[0];
  const float* W_qkv = (const float*)d_in[1];
  const float* b_qkv = (const float*)d_in[2];
  const float* W_out = (const float*)d_in[3];
  const float* b_out = (const float*)d_in[4];
  float* out = (float*)d_out;

  // workspace layout (48 MB total)
  char* ws = (char*)d_ws;
  u16* x_bf   = (u16*)(ws);              //  8 MB  [4096][1024] bf16
  u16* wqkv_t = (u16*)(ws + 8388608);    //  6 MB  [3072][1024] bf16
  u16* wout_t = (u16*)(ws + 14680064);   //  2 MB  [1024][1024] bf16
  u16* q_buf  = (u16*)(ws + 16777216);   //  8 MB  [32][2048][64] bf16
  u16* k_buf  = (u16*)(ws + 25165824);   //  8 MB  [32][2048][64] bf16
  u16* vt_buf = (u16*)(ws + 33554432);   //  8 MB  [32] V-frag fp16 layout
  u16* o_bf   = (u16*)(ws + 41943040);   //  8 MB  [4096][1024] bf16

  prep<<<8192, 256, 0, stream>>>(x, x_bf, W_qkv, wqkv_t, W_out, wout_t);
  gemm_qkv<<<dim3(16, 32), 256, 0, stream>>>(x_bf, wqkv_t, b_qkv,
                                             q_buf, k_buf, vt_buf);
  attn<<<dim3(32, 32), 256, 0, stream>>>(q_buf, k_buf, vt_buf, o_bf);
  gemm_op<<<dim3(16, 32), 256, 0, stream>>>(o_bf, wout_t, b_out, out);
}